// Round 4
// baseline (128.748 us; speedup 1.0000x reference)
//
#include <hip/hip_runtime.h>
#include <math.h>

// Problem constants (from reference setup_inputs)
#define B_    32
#define C_    4
#define N_    16384
#define RES_  32

// One point per thread: 2048 blocks x 256 threads = B*N threads.
#define CHUNKS 64
#define TPB    256
#define GRID   (B_ * CHUNKS)   // 2048

// Fused kernel. Grid XCD-swizzled (id%8 assumed XCD round-robin) so each XCD
// serves 4 batches -> 1.6MB gather working set per XCD L2. Last block (via
// device-scope atomic counter) performs the final fp64 reduction + reg term.
__global__ __launch_bounds__(TPB) void sym_fused(
    const float* __restrict__ y_pred,    // (B, C, 4)
    const float* __restrict__ points,    // (B, N, 3)
    const float* __restrict__ cp,        // (B, RES, RES, RES, 3)
    float* __restrict__ partials,        // GRID floats (d_ws)
    unsigned int* __restrict__ counter,  // 1 uint (d_ws, pre-zeroed via memset)
    float* __restrict__ out)
{
  const int id   = blockIdx.x;
  const int xcd  = id & 7;
  const int slot = id >> 3;                 // 0..255
  const int b     = xcd + 8 * (slot & 3);   // 4 distinct batches per XCD
  const int chunk = slot >> 2;              // 0..63

  // Plane params (uniform across block)
  const float* yp = y_pred + b * (C_ * 4);
  float nx[C_], ny[C_], nz[C_], dd[C_];
#pragma unroll
  for (int c = 0; c < C_; ++c) {
    float ax = yp[c * 4 + 0];
    float ay = yp[c * 4 + 1];
    float az = yp[c * 4 + 2];
    float inv = 1.0f / sqrtf(ax * ax + ay * ay + az * az);
    nx[c] = ax * inv;
    ny[c] = ay * inv;
    nz[c] = az * inv;
    dd[c] = yp[c * 4 + 3];
  }

  const float* pb  = points + (size_t)b * (N_ * 3);
  const float* cpb = cp + (size_t)b * (RES_ * RES_ * RES_ * 3);

  const int p = chunk * TPB + threadIdx.x;   // one point per thread
  const float px = pb[p * 3 + 0];
  const float py = pb[p * 3 + 1];
  const float pz = pb[p * 3 + 2];

  // Phase 1: all 4 reflected vectors + gather indices (no memory deps).
  float rx[C_], ry[C_], rz[C_];
  int lin[C_];
#pragma unroll
  for (int c = 0; c < C_; ++c) {
    float dist = px * nx[c] + py * ny[c] + pz * nz[c] + dd[c];
    float t2 = 2.0f * dist;
    float x = px - t2 * nx[c];
    float y = py - t2 * ny[c];
    float z = pz - t2 * nz[c];
    rx[c] = x; ry[c] = y; rz[c] = z;
    int vx = (int)fminf(fmaxf(floorf(x * (float)RES_), 0.0f), (float)(RES_ - 1));
    int vy = (int)fminf(fmaxf(floorf(y * (float)RES_), 0.0f), (float)(RES_ - 1));
    int vz = (int)fminf(fmaxf(floorf(z * (float)RES_), 0.0f), (float)(RES_ - 1));
    lin[c] = ((vx * RES_ + vy) * RES_ + vz) * 3;
  }

  // Phase 2: all 4 gathers issued back-to-back (dwordx3 each), in flight together.
  float cx[C_], cy[C_], cz[C_];
#pragma unroll
  for (int c = 0; c < C_; ++c) {
    cx[c] = cpb[lin[c] + 0];
    cy[c] = cpb[lin[c] + 1];
    cz[c] = cpb[lin[c] + 2];
  }

  // Phase 3: distances, independent accumulators.
  float a0 = 0.0f, a1 = 0.0f;
#pragma unroll
  for (int c = 0; c < C_; c += 2) {
    float dx0 = rx[c+0] - cx[c+0], dy0 = ry[c+0] - cy[c+0], dz0 = rz[c+0] - cz[c+0];
    float dx1 = rx[c+1] - cx[c+1], dy1 = ry[c+1] - cy[c+1], dz1 = rz[c+1] - cz[c+1];
    a0 += sqrtf(dx0 * dx0 + dy0 * dy0 + dz0 * dz0);
    a1 += sqrtf(dx1 * dx1 + dy1 * dy1 + dz1 * dz1);
  }
  float acc = a0 + a1;

  // Block reduction: wave shuffle, then cross-wave via LDS.
#pragma unroll
  for (int off = 32; off > 0; off >>= 1)
    acc += __shfl_down(acc, off, 64);

  __shared__ float sred[TPB / 64];
  __shared__ bool amLast;
  const int lane = threadIdx.x & 63;
  const int wave = threadIdx.x >> 6;
  if (lane == 0) sred[wave] = acc;
  __syncthreads();
  if (threadIdx.x == 0) {
    float tot = 0.0f;
#pragma unroll
    for (int w = 0; w < TPB / 64; ++w) tot += sred[w];
    partials[id] = tot;
    __threadfence();                         // device-scope release of partial
    unsigned int old = atomicAdd(counter, 1u);
    amLast = (old == (unsigned int)(GRID - 1));
  }
  __syncthreads();
  if (!amLast) return;

  // ---- Last block: final reduction (fp64) + regularizer term ----
  __threadfence();                           // device-scope acquire
  double dacc = 0.0;
  for (int i = threadIdx.x; i < GRID; i += TPB)
    dacc += (double)partials[i];
  dacc *= (1.0 / (double)N_);                // mean over n folded in

  if (threadIdx.x < B_) {
    const int bb = threadIdx.x;
    const float* yq = y_pred + bb * (C_ * 4);
    float nh[C_][3];
#pragma unroll
    for (int c = 0; c < C_; ++c) {
      float ax = yq[c * 4 + 0];
      float ay = yq[c * 4 + 1];
      float az = yq[c * 4 + 2];
      float inv = 1.0f / sqrtf(ax * ax + ay * ay + az * az);
      nh[c][0] = ax * inv;
      nh[c][1] = ay * inv;
      nh[c][2] = az * inv;
    }
    float s = 0.0f;
#pragma unroll
    for (int c = 0; c < C_; ++c) {
#pragma unroll
      for (int e = 0; e < C_; ++e) {
        float dot = nh[c][0] * nh[e][0] + nh[c][1] * nh[e][1] + nh[c][2] * nh[e][2];
        float g = dot - ((c == e) ? 1.0f : 0.0f);
        s += g * g;
      }
    }
    dacc += (25.0 / (double)B_) * (double)sqrtf(s);
  }

  __shared__ double sd[TPB];
  sd[threadIdx.x] = dacc;
  __syncthreads();
  for (int off = TPB / 2; off > 0; off >>= 1) {
    if (threadIdx.x < off) sd[threadIdx.x] += sd[threadIdx.x + off];
    __syncthreads();
  }
  if (threadIdx.x == 0) out[0] = (float)sd[0];
}

extern "C" void kernel_launch(void* const* d_in, const int* in_sizes, int n_in,
                              void* d_out, int out_size, void* d_ws, size_t ws_size,
                              hipStream_t stream) {
  const float* y_pred = (const float*)d_in[0];   // (32,4,4)
  const float* points = (const float*)d_in[1];   // (32,16384,3)
  // d_in[2] = voxel_grid — unused by the reference loss
  const float* cp     = (const float*)d_in[3];   // (32,32,32,32,3)
  float* partials = (float*)d_ws;                          // GRID floats
  unsigned int* counter = (unsigned int*)((char*)d_ws + GRID * sizeof(float));
  float* out = (float*)d_out;

  hipMemsetAsync(counter, 0, sizeof(unsigned int), stream); // ws is 0xAA-poisoned
  sym_fused<<<GRID, TPB, 0, stream>>>(y_pred, points, cp, partials, counter, out);
}

// Round 5
// 85.189 us; speedup vs baseline: 1.5113x; 1.5113x over previous
//
#include <hip/hip_runtime.h>
#include <math.h>

// Problem constants (from reference setup_inputs)
#define B_    32
#define C_    4
#define N_    16384
#define RES_  32

// One point per thread: 2048 blocks x 256 threads = B*N threads.
#define CHUNKS 64
#define TPB    256

// Kernel 1: grid = 2048 1D blocks, XCD-swizzled (id%8 assumed XCD round-robin)
// so each XCD serves 4 batches -> 1.6MB gather working set per XCD L2.
// Gathers + point loads use nontemporal (nt) loads: no L1 allocation -> avoids
// pulling a full cache line into L1 per 12-byte divergent gather.
__global__ __launch_bounds__(TPB) void sym_main(
    const float* __restrict__ y_pred,   // (B, C, 4)
    const float* __restrict__ points,   // (B, N, 3)
    const float* __restrict__ cp,       // (B, RES, RES, RES, 3)
    float* __restrict__ partials)       // (B * CHUNKS)
{
  const int id   = blockIdx.x;
  const int xcd  = id & 7;
  const int slot = id >> 3;                 // 0..255
  const int b     = xcd + 8 * (slot & 3);   // 4 distinct batches per XCD
  const int chunk = slot >> 2;              // 0..63

  // Plane params (uniform across block)
  const float* yp = y_pred + b * (C_ * 4);
  float nx[C_], ny[C_], nz[C_], dd[C_];
#pragma unroll
  for (int c = 0; c < C_; ++c) {
    float ax = yp[c * 4 + 0];
    float ay = yp[c * 4 + 1];
    float az = yp[c * 4 + 2];
    float inv = 1.0f / sqrtf(ax * ax + ay * ay + az * az);
    nx[c] = ax * inv;
    ny[c] = ay * inv;
    nz[c] = az * inv;
    dd[c] = yp[c * 4 + 3];
  }

  const float* pb  = points + (size_t)b * (N_ * 3);
  const float* cpb = cp + (size_t)b * (RES_ * RES_ * RES_ * 3);

  const int p = chunk * TPB + threadIdx.x;   // one point per thread
  const float px = __builtin_nontemporal_load(pb + p * 3 + 0);
  const float py = __builtin_nontemporal_load(pb + p * 3 + 1);
  const float pz = __builtin_nontemporal_load(pb + p * 3 + 2);

  // Phase 1: all 4 reflected vectors + gather indices (no memory deps).
  float rx[C_], ry[C_], rz[C_];
  int lin[C_];
#pragma unroll
  for (int c = 0; c < C_; ++c) {
    float dist = px * nx[c] + py * ny[c] + pz * nz[c] + dd[c];
    float t2 = 2.0f * dist;
    float x = px - t2 * nx[c];
    float y = py - t2 * ny[c];
    float z = pz - t2 * nz[c];
    rx[c] = x; ry[c] = y; rz[c] = z;
    int vx = (int)fminf(fmaxf(floorf(x * (float)RES_), 0.0f), (float)(RES_ - 1));
    int vy = (int)fminf(fmaxf(floorf(y * (float)RES_), 0.0f), (float)(RES_ - 1));
    int vz = (int)fminf(fmaxf(floorf(z * (float)RES_), 0.0f), (float)(RES_ - 1));
    lin[c] = ((vx * RES_ + vy) * RES_ + vz) * 3;
  }

  // Phase 2: all 4 gathers issued back-to-back, nt (bypass L1 allocation).
  float cx[C_], cy[C_], cz[C_];
#pragma unroll
  for (int c = 0; c < C_; ++c) {
    cx[c] = __builtin_nontemporal_load(cpb + lin[c] + 0);
    cy[c] = __builtin_nontemporal_load(cpb + lin[c] + 1);
    cz[c] = __builtin_nontemporal_load(cpb + lin[c] + 2);
  }

  // Phase 3: distances, independent accumulators.
  float a0 = 0.0f, a1 = 0.0f;
#pragma unroll
  for (int c = 0; c < C_; c += 2) {
    float dx0 = rx[c+0] - cx[c+0], dy0 = ry[c+0] - cy[c+0], dz0 = rz[c+0] - cz[c+0];
    float dx1 = rx[c+1] - cx[c+1], dy1 = ry[c+1] - cy[c+1], dz1 = rz[c+1] - cz[c+1];
    a0 += sqrtf(dx0 * dx0 + dy0 * dy0 + dz0 * dz0);
    a1 += sqrtf(dx1 * dx1 + dy1 * dy1 + dz1 * dz1);
  }
  float acc = a0 + a1;

  // Wave (64-lane) shuffle reduction, then cross-wave via LDS
#pragma unroll
  for (int off = 32; off > 0; off >>= 1)
    acc += __shfl_down(acc, off, 64);

  __shared__ float sred[TPB / 64];
  const int lane = threadIdx.x & 63;
  const int wave = threadIdx.x >> 6;
  if (lane == 0) sred[wave] = acc;
  __syncthreads();
  if (threadIdx.x == 0) {
    float tot = 0.0f;
#pragma unroll
    for (int w = 0; w < TPB / 64; ++w) tot += sred[w];
    partials[b * CHUNKS + chunk] = tot;
  }
}

// Kernel 2: single block. Sums the B*CHUNKS partials (fp64 accumulate for
// precision: raw sum is ~5e6), adds REG_COEF * mean_b(reg_loss[b]).
__global__ __launch_bounds__(256) void sym_final(
    const float* __restrict__ y_pred,
    const float* __restrict__ partials,
    float* __restrict__ out)
{
  __shared__ double sd[256];
  double acc = 0.0;
  for (int i = threadIdx.x; i < B_ * CHUNKS; i += 256)
    acc += (double)partials[i];
  acc *= (1.0 / (double)N_);   // mean over n folded into the b,c sum

  if (threadIdx.x < B_) {
    const int b = threadIdx.x;
    const float* yp = y_pred + b * (C_ * 4);
    float nh[C_][3];
#pragma unroll
    for (int c = 0; c < C_; ++c) {
      float ax = yp[c * 4 + 0];
      float ay = yp[c * 4 + 1];
      float az = yp[c * 4 + 2];
      float inv = 1.0f / sqrtf(ax * ax + ay * ay + az * az);
      nh[c][0] = ax * inv;
      nh[c][1] = ay * inv;
      nh[c][2] = az * inv;
    }
    float s = 0.0f;
#pragma unroll
    for (int c = 0; c < C_; ++c) {
#pragma unroll
      for (int e = 0; e < C_; ++e) {
        float dot = nh[c][0] * nh[e][0] + nh[c][1] * nh[e][1] + nh[c][2] * nh[e][2];
        float g = dot - ((c == e) ? 1.0f : 0.0f);
        s += g * g;
      }
    }
    acc += (25.0 / (double)B_) * (double)sqrtf(s);
  }

  sd[threadIdx.x] = acc;
  __syncthreads();
  for (int off = 128; off > 0; off >>= 1) {
    if (threadIdx.x < off) sd[threadIdx.x] += sd[threadIdx.x + off];
    __syncthreads();
  }
  if (threadIdx.x == 0) out[0] = (float)sd[0];
}

extern "C" void kernel_launch(void* const* d_in, const int* in_sizes, int n_in,
                              void* d_out, int out_size, void* d_ws, size_t ws_size,
                              hipStream_t stream) {
  const float* y_pred = (const float*)d_in[0];   // (32,4,4)
  const float* points = (const float*)d_in[1];   // (32,16384,3)
  // d_in[2] = voxel_grid — unused by the reference loss
  const float* cp     = (const float*)d_in[3];   // (32,32,32,32,3)
  float* partials = (float*)d_ws;                // B_*CHUNKS floats
  float* out = (float*)d_out;

  sym_main<<<B_ * CHUNKS, TPB, 0, stream>>>(y_pred, points, cp, partials);
  sym_final<<<1, 256, 0, stream>>>(y_pred, partials, out);
}

// Round 6
// 85.159 us; speedup vs baseline: 1.5119x; 1.0004x over previous
//
#include <hip/hip_runtime.h>
#include <math.h>

// Problem constants (from reference setup_inputs)
#define B_    32
#define C_    4
#define N_    16384
#define RES_  32
#define VOX   (RES_ * RES_ * RES_)   // 32768 voxels per batch

#define CHUNKS 64
#define TPB    256
#define GRID   (B_ * CHUNKS)         // 2048 blocks

// Shared XCD swizzle: id%8 = XCD (assumed round-robin), 4 batches per XCD.
// Both kernels use it, so the repacked table lines land in (and are read from)
// the same XCD's L2.
__device__ __forceinline__ void decode_block(int id, int& b, int& chunk) {
  const int xcd  = id & 7;
  const int slot = id >> 3;
  b     = xcd + 8 * (slot & 3);
  chunk = slot >> 2;
}

// Kernel 0: repack (B,RES,RES,RES,3) float3 -> float4 table in d_ws.
// 2048 blocks x 256 thr x 2 voxels/thread. Leaves table dirty-resident in the
// correct XCD L2 (2.1 MB/XCD < 4 MiB) and makes gathers single-line dwordx4.
__global__ __launch_bounds__(TPB) void repack(
    const float* __restrict__ cp, float4* __restrict__ tab) {
  int b, chunk;
  decode_block(blockIdx.x, b, chunk);
  const float* src = cp + (size_t)b * (VOX * 3);
  float4* dst = tab + (size_t)b * VOX;
#pragma unroll
  for (int k = 0; k < 2; ++k) {
    const int v = chunk * 512 + k * TPB + threadIdx.x;   // 512 voxels/block
    float x = src[v * 3 + 0];
    float y = src[v * 3 + 1];
    float z = src[v * 3 + 2];
    dst[v] = make_float4(x, y, z, 0.0f);
  }
}

// Kernel 1: main gather/accumulate. One point per thread.
__global__ __launch_bounds__(TPB) void sym_main(
    const float* __restrict__ y_pred,   // (B, C, 4)
    const float* __restrict__ points,   // (B, N, 3)
    const float4* __restrict__ tab,     // (B, VOX) repacked, L2-warm
    float* __restrict__ partials)       // (B * CHUNKS)
{
  int b, chunk;
  decode_block(blockIdx.x, b, chunk);

  const float* yp = y_pred + b * (C_ * 4);
  float nx[C_], ny[C_], nz[C_], dd[C_];
#pragma unroll
  for (int c = 0; c < C_; ++c) {
    float ax = yp[c * 4 + 0];
    float ay = yp[c * 4 + 1];
    float az = yp[c * 4 + 2];
    float inv = 1.0f / sqrtf(ax * ax + ay * ay + az * az);
    nx[c] = ax * inv;
    ny[c] = ay * inv;
    nz[c] = az * inv;
    dd[c] = yp[c * 4 + 3];
  }

  const float* pb = points + (size_t)b * (N_ * 3);
  const float4* tb = tab + (size_t)b * VOX;

  const int p = chunk * TPB + threadIdx.x;   // one point per thread
  const float px = pb[p * 3 + 0];
  const float py = pb[p * 3 + 1];
  const float pz = pb[p * 3 + 2];

  // Phase 1: all 4 reflected vectors + gather indices (no memory deps).
  float rx[C_], ry[C_], rz[C_];
  int lin[C_];
#pragma unroll
  for (int c = 0; c < C_; ++c) {
    float dist = px * nx[c] + py * ny[c] + pz * nz[c] + dd[c];
    float t2 = 2.0f * dist;
    float x = px - t2 * nx[c];
    float y = py - t2 * ny[c];
    float z = pz - t2 * nz[c];
    rx[c] = x; ry[c] = y; rz[c] = z;
    int vx = (int)fminf(fmaxf(floorf(x * (float)RES_), 0.0f), (float)(RES_ - 1));
    int vy = (int)fminf(fmaxf(floorf(y * (float)RES_), 0.0f), (float)(RES_ - 1));
    int vz = (int)fminf(fmaxf(floorf(z * (float)RES_), 0.0f), (float)(RES_ - 1));
    lin[c] = (vx * RES_ + vy) * RES_ + vz;
  }

  // Phase 2: 4 gathers, each a single aligned global_load_dwordx4, all in flight.
  float4 cv[C_];
#pragma unroll
  for (int c = 0; c < C_; ++c) cv[c] = tb[lin[c]];

  // Phase 3: distances, independent accumulators.
  float a0 = 0.0f, a1 = 0.0f;
#pragma unroll
  for (int c = 0; c < C_; c += 2) {
    float dx0 = rx[c+0] - cv[c+0].x, dy0 = ry[c+0] - cv[c+0].y, dz0 = rz[c+0] - cv[c+0].z;
    float dx1 = rx[c+1] - cv[c+1].x, dy1 = ry[c+1] - cv[c+1].y, dz1 = rz[c+1] - cv[c+1].z;
    a0 += sqrtf(dx0 * dx0 + dy0 * dy0 + dz0 * dz0);
    a1 += sqrtf(dx1 * dx1 + dy1 * dy1 + dz1 * dz1);
  }
  float acc = a0 + a1;

  // Wave (64-lane) shuffle reduction, then cross-wave via LDS
#pragma unroll
  for (int off = 32; off > 0; off >>= 1)
    acc += __shfl_down(acc, off, 64);

  __shared__ float sred[TPB / 64];
  const int lane = threadIdx.x & 63;
  const int wave = threadIdx.x >> 6;
  if (lane == 0) sred[wave] = acc;
  __syncthreads();
  if (threadIdx.x == 0) {
    float tot = 0.0f;
#pragma unroll
    for (int w = 0; w < TPB / 64; ++w) tot += sred[w];
    partials[b * CHUNKS + chunk] = tot;
  }
}

// Kernel 2: single block. fp64 sum of partials + REG_COEF * mean_b(reg_loss).
__global__ __launch_bounds__(256) void sym_final(
    const float* __restrict__ y_pred,
    const float* __restrict__ partials,
    float* __restrict__ out)
{
  __shared__ double sd[256];
  double acc = 0.0;
  for (int i = threadIdx.x; i < GRID; i += 256)
    acc += (double)partials[i];
  acc *= (1.0 / (double)N_);   // mean over n folded into the b,c sum

  if (threadIdx.x < B_) {
    const int b = threadIdx.x;
    const float* yp = y_pred + b * (C_ * 4);
    float nh[C_][3];
#pragma unroll
    for (int c = 0; c < C_; ++c) {
      float ax = yp[c * 4 + 0];
      float ay = yp[c * 4 + 1];
      float az = yp[c * 4 + 2];
      float inv = 1.0f / sqrtf(ax * ax + ay * ay + az * az);
      nh[c][0] = ax * inv;
      nh[c][1] = ay * inv;
      nh[c][2] = az * inv;
    }
    float s = 0.0f;
#pragma unroll
    for (int c = 0; c < C_; ++c) {
#pragma unroll
      for (int e = 0; e < C_; ++e) {
        float dot = nh[c][0] * nh[e][0] + nh[c][1] * nh[e][1] + nh[c][2] * nh[e][2];
        float g = dot - ((c == e) ? 1.0f : 0.0f);
        s += g * g;
      }
    }
    acc += (25.0 / (double)B_) * (double)sqrtf(s);
  }

  sd[threadIdx.x] = acc;
  __syncthreads();
  for (int off = 128; off > 0; off >>= 1) {
    if (threadIdx.x < off) sd[threadIdx.x] += sd[threadIdx.x + off];
    __syncthreads();
  }
  if (threadIdx.x == 0) out[0] = (float)sd[0];
}

extern "C" void kernel_launch(void* const* d_in, const int* in_sizes, int n_in,
                              void* d_out, int out_size, void* d_ws, size_t ws_size,
                              hipStream_t stream) {
  const float* y_pred = (const float*)d_in[0];   // (32,4,4)
  const float* points = (const float*)d_in[1];   // (32,16384,3)
  // d_in[2] = voxel_grid — unused by the reference loss
  const float* cp     = (const float*)d_in[3];   // (32,32,32,32,3)

  float4* tab = (float4*)d_ws;                            // B_*VOX float4 = 16 MB
  float* partials = (float*)((char*)d_ws + (size_t)B_ * VOX * sizeof(float4));
  float* out = (float*)d_out;

  repack   <<<GRID, TPB, 0, stream>>>(cp, tab);
  sym_main <<<GRID, TPB, 0, stream>>>(y_pred, points, tab, partials);
  sym_final<<<1,    256, 0, stream>>>(y_pred, partials, out);
}